// Round 7
// baseline (415.893 us; speedup 1.0000x reference)
//
#include <hip/hip_runtime.h>
#include <cstdint>
#include <cstddef>

// R7: R6b minus 3 of the 4 per-K-tile barriers in the GEMM.
// Correctness of single-barrier-per-tile on the 4-deep circular buffer:
//  - WAR: every wave retires its reads of buf t (own lgkmcnt(0) before its
//    MFMA-B) BEFORE arriving at tile-t's end barrier; the next write into
//    slot t&3 (stage of tile t+4, issued in tile t+1) is issued only after
//    that barrier's rendezvous -> no clobber.
//  - RAW: per-wave vmcnt(8) retires tile t+1's 4 DMA loads before the tile-t
//    barrier; the rendezvous publishes "t+1 landed" to all waves.
//  - Ledger unchanged: 12 in flight steady-state, tail drains 8->4->0.
// Waves now drift within a tile -> one wave's MFMA covers another's ds_read
// latency (4-barrier lockstep forbade this). Everything else == R6b.

typedef int v4i __attribute__((ext_vector_type(4)));
typedef float v4f __attribute__((ext_vector_type(4)));

__device__ __forceinline__ void async_copy16(const void* g, void* s) {
  __builtin_amdgcn_global_load_lds(
      (const __attribute__((address_space(1))) void*)g,
      (__attribute__((address_space(3))) void*)s, 16, 0, 0);
}

__device__ __forceinline__ float block_max(float m) {
  __shared__ float smax[4];
#pragma unroll
  for (int off = 32; off > 0; off >>= 1)
    m = fmaxf(m, __shfl_down(m, off, 64));
  if ((threadIdx.x & 63) == 0) smax[threadIdx.x >> 6] = m;
  __syncthreads();
  return fmaxf(fmaxf(smax[0], smax[1]), fmaxf(smax[2], smax[3]));
}

#define NBX 1024
#define NBW 512

__global__ __launch_bounds__(256) void absmax_partial_kernel(
    const float4* __restrict__ x, int xn4, const float4* __restrict__ w,
    int wn4, float* __restrict__ px, float* __restrict__ pw) {
  const float4* src;
  float* dst;
  int n4, bid, nb;
  if (blockIdx.x < NBX) {
    src = x; n4 = xn4; dst = px; bid = blockIdx.x; nb = NBX;
  } else {
    src = w; n4 = wn4; dst = pw; bid = blockIdx.x - NBX; nb = NBW;
  }
  float m = 0.0f;
  for (int i = bid * 256 + threadIdx.x; i < n4; i += nb * 256) {
    float4 v = src[i];
    m = fmaxf(m, fmaxf(fmaxf(fabsf(v.x), fabsf(v.y)),
                       fmaxf(fabsf(v.z), fabsf(v.w))));
  }
  m = block_max(m);
  if (threadIdx.x == 0) dst[bid] = m;
}

__device__ __forceinline__ int pack4(float4 v, float inv) {
  int a = (int)fminf(fmaxf(rintf(v.x * inv), -128.0f), 127.0f);
  int b = (int)fminf(fmaxf(rintf(v.y * inv), -128.0f), 127.0f);
  int c = (int)fminf(fmaxf(rintf(v.z * inv), -128.0f), 127.0f);
  int d = (int)fminf(fmaxf(rintf(v.w * inv), -128.0f), 127.0f);
  return (a & 255) | ((b & 255) << 8) | ((c & 255) << 16) | ((d & 255) << 24);
}

#define QNB 2048

__global__ __launch_bounds__(256) void quant_fused_kernel(
    const float4* __restrict__ x, int xn16, const float4* __restrict__ w,
    int wn16, const float* __restrict__ px, const float* __restrict__ pw,
    float* __restrict__ sat, int4* __restrict__ xq, int4* __restrict__ wq) {
  // Self-reduce the absmax partials (no separate final-reduce dispatch).
  float mx = 0.0f, mw = 0.0f;
  for (int i = threadIdx.x; i < NBX; i += 256) mx = fmaxf(mx, px[i]);
  mx = block_max(mx);
  __syncthreads();  // protect smax reuse between the two block_max calls
  for (int i = threadIdx.x; i < NBW; i += 256) mw = fmaxf(mw, pw[i]);
  mw = block_max(mw);
  if (blockIdx.x == 0 && threadIdx.x == 0) {
    sat[0] = mx;  // for the GEMM epilogue
    sat[1] = mw;
  }
  const float invx = 127.0f / fmaxf(mx, 1e-8f);
  const float invw = 127.0f / fmaxf(mw, 1e-8f);

  const int nth = QNB * 256;
  const int t = blockIdx.x * 256 + threadIdx.x;
  for (int u = t; u < xn16; u += nth) {
    const float4* p = x + (size_t)u * 4;
    int4 o;
    o.x = pack4(p[0], invx);
    o.y = pack4(p[1], invx);
    o.z = pack4(p[2], invx);
    o.w = pack4(p[3], invx);
    xq[u] = o;
  }
  for (int u = t; u < wn16; u += nth) {
    const float4* p = w + (size_t)u * 4;
    int4 o;
    o.x = pack4(p[0], invw);
    o.y = pack4(p[1], invw);
    o.z = pack4(p[2], invw);
    o.w = pack4(p[3], invw);
    wq[u] = o;
  }
}

// One K-tile (BK=64 bytes). Single barrier at tile end; per-wave lgkmcnt
// before each MFMA cluster; counted vmcnt (never 0 mid-loop).
#define GEMM_KTILE(CB, SB, T, ST, VMSEL)                                       \
  do {                                                                         \
    const signed char* bA_ = &lds[CB][0][0];                                   \
    const signed char* bB_ = &lds[CB][1][0];                                   \
    signed char* sA_ = &lds[SB][0][0];                                         \
    signed char* sB_ = &lds[SB][1][0];                                         \
    const size_t ko_ = (size_t)((T) + 3) << 6;                                 \
    v4i af_[4], bf_[4], ag_[4];                                                \
    _Pragma("unroll") for (int f = 0; f < 4; ++f) {                            \
      af_[f] = *(const v4i*)(bA_ + (wr * 128 + f * 16 + r15) * 64 + kboff);    \
      bf_[f] = *(const v4i*)(bB_ + (wc * 64 + f * 16 + r15) * 64 + kboff);     \
    }                                                                          \
    if (ST) {                                                                  \
      async_copy16(Ag + ko_, sA_ + d0);                                        \
      async_copy16(Ag + ko_ + rstep, sA_ + d0 + 8192);                         \
    }                                                                          \
    asm volatile("s_waitcnt lgkmcnt(0)" ::: "memory");                         \
    __builtin_amdgcn_sched_barrier(0);                                         \
    __builtin_amdgcn_s_setprio(1);                                             \
    _Pragma("unroll") for (int fm = 0; fm < 4; ++fm)                           \
        _Pragma("unroll") for (int fn = 0; fn < 4; ++fn) acc[fm][fn] =         \
        __builtin_amdgcn_mfma_i32_16x16x64_i8(af_[fm], bf_[fn], acc[fm][fn],   \
                                              0, 0, 0);                        \
    __builtin_amdgcn_s_setprio(0);                                             \
    _Pragma("unroll") for (int f = 0; f < 4; ++f) {                            \
      ag_[f] =                                                                 \
          *(const v4i*)(bA_ + (wr * 128 + 64 + f * 16 + r15) * 64 + kboff);    \
    }                                                                          \
    if (ST) {                                                                  \
      async_copy16(Bg + ko_, sB_ + d0);                                        \
      async_copy16(Bg + ko_ + rstep, sB_ + d0 + 8192);                         \
    }                                                                          \
    asm volatile("s_waitcnt lgkmcnt(0)" ::: "memory");                         \
    __builtin_amdgcn_sched_barrier(0);                                         \
    __builtin_amdgcn_s_setprio(1);                                             \
    _Pragma("unroll") for (int fm = 0; fm < 4; ++fm)                           \
        _Pragma("unroll") for (int fn = 0; fn < 4; ++fn) acc[4 + fm][fn] =     \
        __builtin_amdgcn_mfma_i32_16x16x64_i8(ag_[fm], bf_[fn],                \
                                              acc[4 + fm][fn], 0, 0, 0);       \
    __builtin_amdgcn_s_setprio(0);                                             \
    if ((VMSEL) == 0) {                                                        \
      asm volatile("s_waitcnt vmcnt(8)" ::: "memory");                         \
    } else if ((VMSEL) == 1) {                                                 \
      asm volatile("s_waitcnt vmcnt(4)" ::: "memory");                         \
    } else if ((VMSEL) == 2) {                                                 \
      asm volatile("s_waitcnt vmcnt(0)" ::: "memory");                         \
    }                                                                          \
    __builtin_amdgcn_s_barrier();                                              \
  } while (0)

// C[m,n] = sum_k A[m,k]*B[n,k]; A = x_int8 [M,K], B = w_int8 [N,K].
// 256x256 tile, 512 threads (8 waves: 2Mx4N), BK=64B, 4-deep circular LDS
// K-tile pipeline, counted vmcnt(8), unrolled x4 main loop, 1 barrier/tile.
__global__ __launch_bounds__(512, 2) void i8_gemm_kernel(
    const signed char* __restrict__ Aq, const signed char* __restrict__ Bq,
    const float* __restrict__ bias, const float* __restrict__ sat,
    float* __restrict__ out, int M, int N, int K) {
  __shared__ signed char lds[4][2][256 * 64];  // [buf][A/B][row*64 + chunk*16]

  const int tid = threadIdx.x;
  const int lane = tid & 63;
  const int wid = tid >> 6;  // 0..7
  const int wr = wid >> 2;   // 0..1  (M half)
  const int wc = wid & 3;    // 0..3  (N quarter)
  const int r15 = lane & 15;
  const int q4 = lane >> 4;

  const int nwg = gridDim.x * gridDim.y;
  int bid = blockIdx.y * gridDim.x + blockIdx.x;
  if ((nwg & 7) == 0) bid = (bid & 7) * (nwg >> 3) + (bid >> 3);
  const int N0 = (bid % gridDim.x) * 256;
  const int M0 = (bid / gridDim.x) * 256;

  // Staging (write side): linear LDS dest tid*16 (forced by global_load_lds);
  // slot sb of row srow holds global chunk cg = (sb - ((srow>>1)&3)) & 3.
  const int srow = tid >> 2;  // 0..127
  const int sb = tid & 3;     // chunk slot 0..3
  const int cg = (sb - ((srow >> 1) & 3)) & 3;
  const signed char* Ag = Aq + (size_t)(M0 + srow) * K + cg * 16;
  const signed char* Bg = Bq + (size_t)(N0 + srow) * K + cg * 16;
  const int d0 = srow * 64 + sb * 16;  // == tid*16
  const size_t rstep = (size_t)128 * K;

  // Read side: chunk q4 of row (..+r15) sits at slot (q4+((r15>>1)&3))&3.
  const int kboff = ((q4 + ((r15 >> 1) & 3)) & 3) * 16;

  v4i acc[8][4] = {};
  const int nt = K >> 6;

  // Prologue: stage tiles 0,1,2 (4 loads/thread each).
  for (int T = 0; T < 3; ++T) {
    const size_t ko = (size_t)T << 6;
    signed char* bA = &lds[T & 3][0][0];
    signed char* bB = &lds[T & 3][1][0];
    async_copy16(Ag + ko, bA + d0);
    async_copy16(Ag + ko + rstep, bA + d0 + 8192);
    async_copy16(Bg + ko, bB + d0);
    async_copy16(Bg + ko + rstep, bB + d0 + 8192);
  }
  asm volatile("s_waitcnt vmcnt(8)" ::: "memory");  // tile 0 landed
  __builtin_amdgcn_s_barrier();

  // Main loop unrolled x4: buffer indices are compile-time (t0 % 4 == 0).
  int t = 0;
  for (; t + 7 < nt; t += 4) {
    GEMM_KTILE(0, 3, t + 0, true, 0);
    GEMM_KTILE(1, 0, t + 1, true, 0);
    GEMM_KTILE(2, 1, t + 2, true, 0);
    GEMM_KTILE(3, 2, t + 3, true, 0);
  }
  // Tail (<= 7 tiles): runtime buffer select + vmcnt drain 8 -> 4 -> 0.
  for (; t < nt; ++t) {
    const int cb = t & 3;
    const int sbuf = (t + 3) & 3;
    const bool st = (t + 3) < nt;
    const int vmsel =
        (t < nt - 3) ? 0 : (t == nt - 3) ? 1 : (t == nt - 2) ? 2 : 3;
    GEMM_KTILE(cb, sbuf, t, st, vmsel);
  }

  const float act_s = fmaxf(sat[0], 1e-8f) / 127.0f;
  const float w_s = fmaxf(sat[1], 1e-8f) / 127.0f;
  const float bscale = act_s * w_s;

  // Coalesced epilogue. Per-wave-private 16KB LDS scratch (safe: final tile's
  // end barrier saw every wave's lgkmcnt(0) + vmcnt drained to 0).
  // MFMA C/D layout: col = lane&15 (=r15), row = q4*4 + reg. Scatter acc into
  // scratch[64][64] f32, read back 16B/lane row-contiguous, store full 256B
  // row segments. lgkmcnt is wave-scoped -> no barrier needed.
  float* scratch = (float*)&lds[0][0][0] + wid * 4096;
  const float4 b4 = *(const float4*)&bias[N0 + wc * 64 + 4 * r15];
  v4f fb4;
  fb4.x = rintf(b4.x / bscale);
  fb4.y = rintf(b4.y / bscale);
  fb4.z = rintf(b4.z / bscale);
  fb4.w = rintf(b4.w / bscale);

#pragma unroll
  for (int g = 0; g < 2; ++g) {
#pragma unroll
    for (int f4 = 0; f4 < 4; ++f4)
#pragma unroll
      for (int fn = 0; fn < 4; ++fn)
#pragma unroll
        for (int rr = 0; rr < 4; ++rr)
          scratch[(f4 * 16 + q4 * 4 + rr) * 64 + fn * 16 + r15] =
              (float)acc[g * 4 + f4][fn][rr];
    // compiler emits lgkmcnt wait for the may-alias RAW on scratch
#pragma unroll
    for (int rq = 0; rq < 16; ++rq) {
      v4f v = *(v4f*)&scratch[(rq * 4 + q4) * 64 + 4 * r15];
      v4f o = (v + fb4) * bscale;
      const int row = M0 + wr * 128 + g * 64 + rq * 4 + q4;
      __builtin_nontemporal_store(
          o, (v4f*)&out[(size_t)row * N + N0 + wc * 64 + 4 * r15]);
    }
  }
}

extern "C" void kernel_launch(void* const* d_in, const int* in_sizes, int n_in,
                              void* d_out, int out_size, void* d_ws,
                              size_t ws_size, hipStream_t stream) {
  const float* x = (const float*)d_in[0];
  const float* W = (const float*)d_in[1];
  const float* b = (const float*)d_in[2];
  float* out = (float*)d_out;

  const int Dout = in_sizes[2];      // 4096
  const int K = in_sizes[1] / Dout;  // 4096
  const int M = in_sizes[0] / K;     // 8192
  const int N = Dout;

  float* sat = (float*)d_ws;
  float* px = sat + 16;
  float* pw = px + NBX;
  signed char* xq = (signed char*)d_ws + 8192;
  signed char* wq = xq + (size_t)M * K;

  const int xn4 = in_sizes[0] / 4;
  const int wn4 = in_sizes[1] / 4;

  absmax_partial_kernel<<<NBX + NBW, 256, 0, stream>>>(
      (const float4*)x, xn4, (const float4*)W, wn4, px, pw);
  quant_fused_kernel<<<QNB, 256, 0, stream>>>(
      (const float4*)x, xn4 / 4, (const float4*)W, wn4 / 4, px, pw, sat,
      (int4*)xq, (int4*)wq);

  dim3 grid(N / 256, M / 256);
  i8_gemm_kernel<<<grid, 512, 0, stream>>>(xq, wq, b, sat, out, M, N, K);
}